// Round 6
// baseline (146.227 us; speedup 1.0000x reference)
//
#include <hip/hip_runtime.h>

#define IMG 192

// ===========================================================================
// Fused x+y pass, one kernel per scale.
// Block = (z, ox-tile). Stages raw rows in LDS (CHUNK rows at a time),
// computes x-box-sums for 5 channels into sx[5][192][TXP], then y-box-sums
// from sx and writes B2 directly. B1 is eliminated.
// B2 layout per scale: [c][z][oy][PO] floats (PO = padded O, mult of 4).
//   scale0: O=57 PO=60  base 0         CV=192*57*60=656640*5
//   scale1: O=25 PO=28  base 3283200
//   scale2: O=9  PO=12  base 3955200   (total 4,058,880 floats)
// ===========================================================================
template<int O, int PO, int S, int K, int TX, int TXP, int SPAN, int CHUNK, int NT>
__global__ __launch_bounds__(256) void fuseXY(
    const float* __restrict__ I, const float* __restrict__ T,
    float* __restrict__ B2)
{
    __shared__ __align__(16) float rawI[CHUNK][SPAN];
    __shared__ __align__(16) float rawT[CHUNK][SPAN];
    __shared__ float sx[5][IMG][TXP];

    const int tid  = threadIdx.x;
    const int z    = blockIdx.x / NT;
    const int tile = blockIdx.x - z * NT;
    const int ox0  = tile * TX;
    const int TXe  = (O - ox0 < TX) ? (O - ox0) : TX;
    const int x0   = ox0 * S;
    const int X0   = x0 & ~3;          // float4-aligned staging origin
    const int DX   = x0 - X0;          // 0..3

    constexpr int SPV = SPAN / 4;
    const float4* Iv = (const float4*)I;
    const float4* Tv = (const float4*)T;

    for (int ch = 0; ch < IMG / CHUNK; ++ch) {
        // ---- stage CHUNK rows of the x-window (coalesced float4) ----
        const size_t rowbase = ((size_t)z * IMG + ch * CHUNK) * (IMG / 4);
        for (int t = tid; t < CHUNK * SPV; t += 256) {
            int r = t / SPV, v = t - r * SPV;
            int gx = (X0 >> 2) + v;
            float4 a = make_float4(0.f, 0.f, 0.f, 0.f), b = a;
            if (gx < IMG / 4) {
                a = Iv[rowbase + (size_t)r * (IMG / 4) + gx];
                b = Tv[rowbase + (size_t)r * (IMG / 4) + gx];
            }
            ((float4*)&rawI[r][0])[v] = a;
            ((float4*)&rawT[r][0])[v] = b;
        }
        __syncthreads();
        // ---- x-sums for these rows, 5 channels fused ----
        for (int t = tid; t < CHUNK * TX; t += 256) {
            int r = t / TX, tx = t - r * TX;
            const float* a = &rawI[r][DX + tx * S];
            const float* b = &rawT[r][DX + tx * S];
            float sI = 0.f, sT = 0.f, sI2 = 0.f, sT2 = 0.f, sIT = 0.f;
#pragma unroll 8
            for (int i = 0; i < K; ++i) {
                float x = a[2 * i], y = b[2 * i];
                sI += x; sT += y; sI2 += x * x; sT2 += y * y; sIT += x * y;
            }
            int y = ch * CHUNK + r;
            sx[0][y][tx] = sI;
            sx[1][y][tx] = sT;
            sx[2][y][tx] = sI2;
            sx[3][y][tx] = sT2;
            sx[4][y][tx] = sIT;
        }
        __syncthreads();
    }

    // ---- y-pass from sx, write B2 ----
    for (int t = tid; t < 5 * O * TX; t += 256) {
        int c  = t / (O * TX);
        int r2 = t - c * (O * TX);
        int oy = r2 / TX;
        int tx = r2 - oy * TX;
        if (tx < TXe) {
            float acc = 0.f;
#pragma unroll 8
            for (int j = 0; j < K; ++j) acc += sx[c][oy * S + 2 * j][tx];
            B2[(size_t)c * (IMG * O * PO) + ((size_t)z * O + oy) * PO + ox0 + tx] = acc;
        }
    }
}

// ---------------------------------------------------------------------------
// Pass 3 (z-direction): per-channel, single float4 accumulator, low VGPR.
// B3 layout per scale: [ch][n3v] float4; bases(fl) {0, 974700, 1062200}.
// ---------------------------------------------------------------------------
template<int O, int PO, int S, int K>
__device__ __forceinline__ void passZc(const float* __restrict__ B2,
                                       float4* __restrict__ B3, int idx) {
    constexpr int POV = PO / 4;
    constexpr int CV  = IMG * O * POV;
    constexpr int N3V = O * O * POV;
    if (idx >= 5 * N3V) return;
    int c   = idx / N3V;
    int rv  = idx - c * N3V;
    int ox4 = rv % POV;
    int t   = rv / POV;
    int oy  = t % O;
    int oz  = t / O;
    const float4* p = (const float4*)B2 + (size_t)c * CV
                      + (size_t)(oz * S) * O * POV + (size_t)oy * POV + ox4;
    float4 acc = make_float4(0.f, 0.f, 0.f, 0.f);
#pragma unroll 8
    for (int l = 0; l < K; ++l) {
        float4 v = p[(size_t)l * 2 * O * POV];
        acc.x += v.x; acc.y += v.y; acc.z += v.z; acc.w += v.w;
    }
    B3[idx] = acc;
}

__global__ __launch_bounds__(256) void passZ_all(
    const float* __restrict__ B2, float* __restrict__ B3)
{
    const int b = blockIdx.x;
    if (b < 952)
        passZc<57, 60, 3, 12>(B2, (float4*)B3, b * 256 + threadIdx.x);
    else if (b < 1038)
        passZc<25, 28, 6, 24>(B2 + 3283200, (float4*)(B3 + 974700),
                              (b - 952) * 256 + threadIdx.x);
    else
        passZc<9, 12, 12, 48>(B2 + 3955200, (float4*)(B3 + 1062200),
                              (b - 1038) * 256 + threadIdx.x);
}

// ---------------------------------------------------------------------------
// LNCC + weighted partial reduce over padded B3.
// ---------------------------------------------------------------------------
__device__ __forceinline__ float lncc1(float i_s, float t_s, float i2, float t2,
                                       float it, float inv_numel) {
    float cross = it - i_s * t_s * inv_numel;
    float iv    = i2 - i_s * i_s * inv_numel;
    float tv    = t2 - t_s * t_s * inv_numel;
    return cross * cross / (iv * tv + 1e-5f);
}

template<int O, int PO>
__device__ __forceinline__ float red_impl(const float* __restrict__ B3,
                                          int rv, float inv_numel, float wdiv) {
    constexpr int POV = PO / 4;
    constexpr int N3V = O * O * POV;
    const float4* p = (const float4*)B3;
    float4 s0 = p[rv];
    float4 s1 = p[(size_t)1 * N3V + rv];
    float4 s2 = p[(size_t)2 * N3V + rv];
    float4 s3 = p[(size_t)3 * N3V + rv];
    float4 s4 = p[(size_t)4 * N3V + rv];
    int ox = (rv % POV) * 4;
    float local = 0.f;
    if (ox + 0 < O) local += lncc1(s0.x, s1.x, s2.x, s3.x, s4.x, inv_numel);
    if (ox + 1 < O) local += lncc1(s0.y, s1.y, s2.y, s3.y, s4.y, inv_numel);
    if (ox + 2 < O) local += lncc1(s0.z, s1.z, s2.z, s3.z, s4.z, inv_numel);
    if (ox + 3 < O) local += lncc1(s0.w, s1.w, s2.w, s3.w, s4.w, inv_numel);
    return local * wdiv;
}

__global__ __launch_bounds__(256) void reduce_all(
    const float* __restrict__ B3, float* __restrict__ partials)
{
    const int b = blockIdx.x;
    float v = 0.f;
    if (b < 191) {
        int r = b * 256 + threadIdx.x;
        if (r < 48735)
            v = red_impl<57, 60>(B3, r, 1.f / 1728.f, 0.1f / 185193.f);
    } else if (b < 209) {
        int r = (b - 191) * 256 + threadIdx.x;
        if (r < 4375)
            v = red_impl<25, 28>(B3 + 974700, r, 1.f / 13824.f, 0.3f / 15625.f);
    } else {
        int r = (b - 209) * 256 + threadIdx.x;
        if (r < 243)
            v = red_impl<9, 12>(B3 + 1062200, r, 1.f / 110592.f, 0.6f / 729.f);
    }
    __shared__ float red[256];
    red[threadIdx.x] = v;
    __syncthreads();
    for (int o = 128; o > 0; o >>= 1) {
        if (threadIdx.x < o) red[threadIdx.x] += red[threadIdx.x + o];
        __syncthreads();
    }
    if (threadIdx.x == 0) partials[blockIdx.x] = red[0];
}

__global__ __launch_bounds__(256) void finalize_n(
    const float* __restrict__ partials, int n, float* __restrict__ out)
{
    float v = 0.f;
    for (int i = threadIdx.x; i < n; i += 256) v += partials[i];
    __shared__ float red[256];
    red[threadIdx.x] = v;
    __syncthreads();
    for (int o = 128; o > 0; o >>= 1) {
        if (threadIdx.x < o) red[threadIdx.x] += red[threadIdx.x + o];
        __syncthreads();
    }
    if (threadIdx.x == 0) out[0] = 1.0f - red[0];
}

// ------------------- fallback kernels (small-ws path) ----------------------
__global__ void pass1_one(const float* __restrict__ I, const float* __restrict__ T,
                          float* __restrict__ B1, int O, int s, int k, int c) {
    int idx = blockIdx.x * blockDim.x + threadIdx.x;
    if (idx >= IMG * IMG * O) return;
    int ox = idx % O;
    int zy = idx / O;
    const float* pI = I + (size_t)zy * IMG + ox * s;
    const float* pT = T + (size_t)zy * IMG + ox * s;
    float acc = 0.f;
    for (int i = 0; i < k; ++i) {
        float v;
        if (c == 0)      v = pI[2 * i];
        else if (c == 1) v = pT[2 * i];
        else if (c == 2) { float a = pI[2 * i]; v = a * a; }
        else if (c == 3) { float bb = pT[2 * i]; v = bb * bb; }
        else             { v = pI[2 * i] * pT[2 * i]; }
        acc += v;
    }
    B1[idx] = acc;
}

__global__ void pass_y(const float* __restrict__ Bin, float* __restrict__ Bout,
                       int O, int s, int k, int n1, int n2) {
    int idx = blockIdx.x * blockDim.x + threadIdx.x;
    if (idx >= n2) return;
    int ox = idx % O;
    int t  = idx / O;
    int oy = t % O;
    int z  = t / O;
    const float* p = Bin + (size_t)z * IMG * O + (size_t)(oy * s) * O + ox;
    float acc = 0.f;
    for (int j = 0; j < k; ++j) acc += p[(size_t)j * 2 * O];
    Bout[idx] = acc;
}

__global__ void pass_z(const float* __restrict__ Bin, float* __restrict__ Bout,
                       int O, int s, int k, int n2, int n3) {
    int idx = blockIdx.x * blockDim.x + threadIdx.x;
    if (idx >= n3) return;
    int ox = idx % O;
    int t  = idx / O;
    int oy = t % O;
    int oz = t / O;
    const float* p = Bin + (size_t)(oz * s) * O * O + (size_t)oy * O + ox;
    float acc = 0.f;
    for (int l = 0; l < k; ++l) acc += p[(size_t)l * 2 * O * O];
    Bout[idx] = acc;
}

__global__ void reduce_one(const float* __restrict__ B3, int n3, float inv_numel,
                           float wdiv, float* __restrict__ partials) {
    float local = 0.f;
    for (int i = blockIdx.x * 256 + threadIdx.x; i < n3; i += gridDim.x * 256) {
        float i_s = B3[i];
        float t_s = B3[(size_t)n3 + i];
        float i2  = B3[2 * (size_t)n3 + i];
        float t2  = B3[3 * (size_t)n3 + i];
        float it  = B3[4 * (size_t)n3 + i];
        local += wdiv * lncc1(i_s, t_s, i2, t2, it, inv_numel);
    }
    __shared__ float red[256];
    red[threadIdx.x] = local;
    __syncthreads();
    for (int o = 128; o > 0; o >>= 1) {
        if (threadIdx.x < o) red[threadIdx.x] += red[threadIdx.x + o];
        __syncthreads();
    }
    if (threadIdx.x == 0) partials[blockIdx.x] += red[0];
}

__global__ void zero_buf(float* __restrict__ p, int n) {
    int i = blockIdx.x * 256 + threadIdx.x;
    if (i < n) p[i] = 0.f;
}

// ---------------------------------------------------------------------------
extern "C" void kernel_launch(void* const* d_in, const int* in_sizes, int n_in,
                              void* d_out, int out_size, void* d_ws, size_t ws_size,
                              hipStream_t stream) {
    const float* I = (const float*)d_in[0];
    const float* T = (const float*)d_in[1];
    float* out = (float*)d_out;
    float* ws  = (float*)d_ws;

    const size_t szB2p = 4058880;    // padded B2 floats
    const size_t szB3p = 1067060;    // padded B3 floats
    const size_t need  = (szB2p + szB3p + 1024) * sizeof(float);   // ~20.5 MB

    if (ws_size >= need) {
        float* B2 = ws;
        float* B3 = B2 + szB2p;
        float* partials = B3 + szB3p;
        // scale0: O=57 PO=60 S=3  K=12 TX=15 TXP=16 SPAN=68  CHUNK=32 NT=4
        fuseXY<57, 60, 3, 12, 15, 16, 68, 32, 4><<<192 * 4, 256, 0, stream>>>(I, T, B2);
        // scale1: O=25 PO=28 S=6  K=24 TX=9  TXP=10 SPAN=100 CHUNK=32 NT=3
        fuseXY<25, 28, 6, 24, 9, 10, 100, 32, 3><<<192 * 3, 256, 0, stream>>>(I, T, B2 + 3283200);
        // scale2: O=9  PO=12 S=12 K=48 TX=9  TXP=10 SPAN=196 CHUNK=16 NT=1
        fuseXY<9, 12, 12, 48, 9, 10, 196, 16, 1><<<192, 256, 0, stream>>>(I, T, B2 + 3955200);
        passZ_all<<<1043, 256, 0, stream>>>(B2, B3);
        reduce_all<<<210, 256, 0, stream>>>(B3, partials);
        finalize_n<<<1, 256, 0, stream>>>(partials, 210, out);
    } else {
        // minimal-ws path: per scale, per channel pipelines (scalar, unpadded)
        const int   Ks[3] = {12, 24, 48};
        const int   Ss[3] = {3, 6, 12};
        const int   Os[3] = {57, 25, 9};
        const int   N1[3] = {2101248, 921600, 331776};
        const int   N2[3] = {623808, 120000, 15552};
        const int   N3[3] = {185193, 15625, 729};
        const float Wt[3] = {0.1f, 0.3f, 0.6f};

        float* B1 = ws;                 // n1_max = 2101248
        float* B2 = B1 + 2101248;       // n2_max = 623808
        float* B3 = B2 + 623808;        // 5 * n3_max = 925965
        float* partials = B3 + 925965;  // 256

        zero_buf<<<1, 256, 0, stream>>>(partials, 256);
        for (int sc = 0; sc < 3; ++sc) {
            int k = Ks[sc], s = Ss[sc], O = Os[sc];
            int n1 = N1[sc], n2 = N2[sc], n3 = N3[sc];
            for (int c = 0; c < 5; ++c) {
                pass1_one<<<(n1 + 255) / 256, 256, 0, stream>>>(I, T, B1, O, s, k, c);
                pass_y<<<(n2 + 255) / 256, 256, 0, stream>>>(B1, B2, O, s, k, n1, n2);
                pass_z<<<(n3 + 255) / 256, 256, 0, stream>>>(B2, B3 + (size_t)c * n3, O, s, k, n2, n3);
            }
            int nblk = (n3 + 255) / 256; if (nblk > 256) nblk = 256;
            reduce_one<<<nblk, 256, 0, stream>>>(B3, n3, 1.f / ((float)k * k * k),
                                                 Wt[sc] / (float)n3, partials);
        }
        finalize_n<<<1, 256, 0, stream>>>(partials, 256, out);
    }
}

// Round 7
// 60.684 us; speedup vs baseline: 2.4096x; 2.4096x over previous
//
#include <hip/hip_runtime.h>

#define IMG 192
#define ROWP 196      // padded LDS row stride (floats)
#define CS1 2211840   // B1 channel stride = 36864*60
// B1: [5][zy=36864][60]  = 11,059,200 fl (44.2 MB)
// B2: [5][z=192][oy=57][60] = 3,283,200 fl (13.1 MB)
// B3: [5][oz=57][oy=57][60] =   974,700 fl (3.9 MB)

// ---------------------------------------------------------------------------
// Pass 1: x-box-sums for SCALE 0 ONLY (k=12, dil=2, stride=3), LDS-staged.
// ---------------------------------------------------------------------------
__global__ __launch_bounds__(256) void pass1_s0(
    const float* __restrict__ I, const float* __restrict__ T,
    float* __restrict__ B1)
{
    __shared__ float lI[8 * ROWP];
    __shared__ float lT[8 * ROWP];
    const int tid = threadIdx.x;
    const int r0  = blockIdx.x * 8;                 // first zy row

    const float4* I4 = (const float4*)(I + (size_t)r0 * IMG);
    const float4* T4 = (const float4*)(T + (size_t)r0 * IMG);
    float4* lI4 = (float4*)lI;
    float4* lT4 = (float4*)lT;
    for (int t = tid; t < 8 * (IMG / 4); t += 256) {   // 384 float4
        int row = t / 48, xi = t - row * 48;
        lI4[row * (ROWP / 4) + xi] = I4[t];
        lT4[row * (ROWP / 4) + xi] = T4[t];
    }
    __syncthreads();

    for (int w = tid; w < 8 * 57; w += 256) {
        int row = w / 57, ox = w - row * 57;
        const float* a = &lI[row * ROWP + ox * 3];
        const float* b = &lT[row * ROWP + ox * 3];
        float sI = 0.f, sT = 0.f, sI2 = 0.f, sT2 = 0.f, sIT = 0.f;
#pragma unroll
        for (int i = 0; i < 12; ++i) {
            float x = a[2 * i], y = b[2 * i];
            sI += x; sT += y; sI2 += x * x; sT2 += y * y; sIT += x * y;
        }
        size_t o = (size_t)(r0 + row) * 60 + ox;
        B1[o]            = sI;
        B1[CS1 + o]      = sT;
        B1[2 * CS1 + o]  = sI2;
        B1[3 * CS1 + o]  = sT2;
        B1[4 * CS1 + o]  = sIT;
    }
}

// ---------------------------------------------------------------------------
// Pass 2 (y), scale0, float4: B1[c][z*192+3oy+2j][60] -> B2[c][z][oy][60].
// ---------------------------------------------------------------------------
__global__ __launch_bounds__(256) void passY_s0(
    const float* __restrict__ B1, float4* __restrict__ B2)
{
    constexpr int POV = 15;                 // 60/4
    constexpr int CV  = IMG * 57 * POV;     // 164160 float4 per channel
    int idx = blockIdx.x * 256 + threadIdx.x;
    if (idx >= 5 * CV) return;
    int c   = idx / CV;
    int r   = idx - c * CV;
    int ox4 = r % POV;
    int t   = r / POV;
    int oy  = t % 57;
    int z   = t / 57;
    const float4* p = (const float4*)(B1 + (size_t)c * CS1
                       + ((size_t)z * IMG + (size_t)oy * 3) * 60) + ox4;
    float4 acc = make_float4(0.f, 0.f, 0.f, 0.f);
#pragma unroll
    for (int j = 0; j < 12; ++j) {
        float4 v = p[(size_t)j * 2 * POV];
        acc.x += v.x; acc.y += v.y; acc.z += v.z; acc.w += v.w;
    }
    B2[idx] = acc;
}

// ---------------------------------------------------------------------------
// Pass 3 (z), scale0, float4: B2[c][3oz+2l][oy][60] -> B3[c][oz][oy][60].
// ---------------------------------------------------------------------------
__global__ __launch_bounds__(256) void passZ_s0(
    const float* __restrict__ B2, float4* __restrict__ B3)
{
    constexpr int POV = 15;
    constexpr int CV  = IMG * 57 * POV;
    constexpr int N3V = 57 * 57 * POV;      // 48735 float4 per channel
    int idx = blockIdx.x * 256 + threadIdx.x;
    if (idx >= 5 * N3V) return;
    int c   = idx / N3V;
    int rv  = idx - c * N3V;
    int ox4 = rv % POV;
    int t   = rv / POV;
    int oy  = t % 57;
    int oz  = t / 57;
    const float4* p = (const float4*)B2 + (size_t)c * CV
                      + (size_t)(oz * 3) * 57 * POV + (size_t)oy * POV + ox4;
    float4 acc = make_float4(0.f, 0.f, 0.f, 0.f);
#pragma unroll
    for (int l = 0; l < 12; ++l) {
        float4 v = p[(size_t)l * 2 * 57 * POV];
        acc.x += v.x; acc.y += v.y; acc.z += v.z; acc.w += v.w;
    }
    B3[idx] = acc;
}

// ---------------------------------------------------------------------------
// LNCC helpers + scale-1/2 derivation from B3 (exact window decomposition).
// ---------------------------------------------------------------------------
__device__ __forceinline__ float lncc1(float i_s, float t_s, float i2, float t2,
                                       float it, float inv_numel) {
    float cross = it - i_s * t_s * inv_numel;
    float iv    = i2 - i_s * i_s * inv_numel;
    float tv    = t2 - t_s * t_s * inv_numel;
    return cross * cross / (iv * tv + 1e-5f);
}

// scale0: vectorized over padded B3
__device__ __forceinline__ float red_s0(const float* __restrict__ B3, int rv,
                                        float inv_numel, float wdiv) {
    constexpr int POV = 15;
    constexpr int N3V = 57 * 57 * POV;
    const float4* p = (const float4*)B3;
    float4 s0 = p[rv];
    float4 s1 = p[(size_t)1 * N3V + rv];
    float4 s2 = p[(size_t)2 * N3V + rv];
    float4 s3 = p[(size_t)3 * N3V + rv];
    float4 s4 = p[(size_t)4 * N3V + rv];
    int ox = (rv % POV) * 4;
    float local = 0.f;
    if (ox + 0 < 57) local += lncc1(s0.x, s1.x, s2.x, s3.x, s4.x, inv_numel);
    if (ox + 1 < 57) local += lncc1(s0.y, s1.y, s2.y, s3.y, s4.y, inv_numel);
    if (ox + 2 < 57) local += lncc1(s0.z, s1.z, s2.z, s3.z, s4.z, inv_numel);
    if (ox + 3 < 57) local += lncc1(s0.w, s1.w, s2.w, s3.w, s4.w, inv_numel);
    return local * wdiv;
}

// scale1 (DN=2, M=2) / scale2 (DN=4, M=4): gather DN^3 scale0 sums per channel
template<int DN, int M>
__device__ __forceinline__ float derive_lncc(const float* __restrict__ B3,
                                             int r, int O1,
                                             float inv_numel, float wdiv) {
    int ox = r % O1;
    int t  = r / O1;
    int oy = t % O1;
    int oz = t / O1;
    float s[5];
    for (int c = 0; c < 5; ++c) {
        float acc = 0.f;
        for (int iz = 0; iz < DN; ++iz)
            for (int iy = 0; iy < DN; ++iy) {
                const float* p = B3
                    + (((size_t)c * 57 + (M * oz + 8 * iz)) * 57
                       + (M * oy + 8 * iy)) * 60 + M * ox;
#pragma unroll
                for (int ix = 0; ix < DN; ++ix) acc += p[8 * ix];
            }
        s[c] = acc;
    }
    return wdiv * lncc1(s[0], s[1], s[2], s[3], s[4], inv_numel);
}

__global__ __launch_bounds__(256) void reduce_all(
    const float* __restrict__ B3, float* __restrict__ partials)
{
    const int b = blockIdx.x;
    float v = 0.f;
    if (b < 191) {                                   // scale0: 48735 float4
        int r = b * 256 + threadIdx.x;
        if (r < 48735) v = red_s0(B3, r, 1.f / 1728.f, 0.1f / 185193.f);
    } else if (b < 253) {                            // scale1: 15625 outputs
        int r = (b - 191) * 256 + threadIdx.x;
        if (r < 15625)
            v = derive_lncc<2, 2>(B3, r, 25, 1.f / 13824.f, 0.3f / 15625.f);
    } else {                                         // scale2: 729 outputs
        int r = (b - 253) * 256 + threadIdx.x;
        if (r < 729)
            v = derive_lncc<4, 4>(B3, r, 9, 1.f / 110592.f, 0.6f / 729.f);
    }
    __shared__ float red[256];
    red[threadIdx.x] = v;
    __syncthreads();
    for (int o = 128; o > 0; o >>= 1) {
        if (threadIdx.x < o) red[threadIdx.x] += red[threadIdx.x + o];
        __syncthreads();
    }
    if (threadIdx.x == 0) partials[blockIdx.x] = red[0];
}

__global__ __launch_bounds__(256) void finalize_n(
    const float* __restrict__ partials, int n, float* __restrict__ out)
{
    float v = 0.f;
    for (int i = threadIdx.x; i < n; i += 256) v += partials[i];
    __shared__ float red[256];
    red[threadIdx.x] = v;
    __syncthreads();
    for (int o = 128; o > 0; o >>= 1) {
        if (threadIdx.x < o) red[threadIdx.x] += red[threadIdx.x + o];
        __syncthreads();
    }
    if (threadIdx.x == 0) out[0] = 1.0f - red[0];
}

// ------------------- fallback kernels (small-ws path) ----------------------
__global__ void pass1_one(const float* __restrict__ I, const float* __restrict__ T,
                          float* __restrict__ B1, int O, int s, int k, int c) {
    int idx = blockIdx.x * blockDim.x + threadIdx.x;
    if (idx >= IMG * IMG * O) return;
    int ox = idx % O;
    int zy = idx / O;
    const float* pI = I + (size_t)zy * IMG + ox * s;
    const float* pT = T + (size_t)zy * IMG + ox * s;
    float acc = 0.f;
    for (int i = 0; i < k; ++i) {
        float v;
        if (c == 0)      v = pI[2 * i];
        else if (c == 1) v = pT[2 * i];
        else if (c == 2) { float a = pI[2 * i]; v = a * a; }
        else if (c == 3) { float bb = pT[2 * i]; v = bb * bb; }
        else             { v = pI[2 * i] * pT[2 * i]; }
        acc += v;
    }
    B1[idx] = acc;
}

__global__ void pass_y(const float* __restrict__ Bin, float* __restrict__ Bout,
                       int O, int s, int k, int n1, int n2) {
    int idx = blockIdx.x * blockDim.x + threadIdx.x;
    if (idx >= n2) return;
    int ox = idx % O;
    int t  = idx / O;
    int oy = t % O;
    int z  = t / O;
    const float* p = Bin + (size_t)z * IMG * O + (size_t)(oy * s) * O + ox;
    float acc = 0.f;
    for (int j = 0; j < k; ++j) acc += p[(size_t)j * 2 * O];
    Bout[idx] = acc;
}

__global__ void pass_z(const float* __restrict__ Bin, float* __restrict__ Bout,
                       int O, int s, int k, int n2, int n3) {
    int idx = blockIdx.x * blockDim.x + threadIdx.x;
    if (idx >= n3) return;
    int ox = idx % O;
    int t  = idx / O;
    int oy = t % O;
    int oz = t / O;
    const float* p = Bin + (size_t)(oz * s) * O * O + (size_t)oy * O + ox;
    float acc = 0.f;
    for (int l = 0; l < k; ++l) acc += p[(size_t)l * 2 * O * O];
    Bout[idx] = acc;
}

__global__ void reduce_one(const float* __restrict__ B3, int n3, float inv_numel,
                           float wdiv, float* __restrict__ partials) {
    float local = 0.f;
    for (int i = blockIdx.x * 256 + threadIdx.x; i < n3; i += gridDim.x * 256) {
        float i_s = B3[i];
        float t_s = B3[(size_t)n3 + i];
        float i2  = B3[2 * (size_t)n3 + i];
        float t2  = B3[3 * (size_t)n3 + i];
        float it  = B3[4 * (size_t)n3 + i];
        local += wdiv * lncc1(i_s, t_s, i2, t2, it, inv_numel);
    }
    __shared__ float red[256];
    red[threadIdx.x] = local;
    __syncthreads();
    for (int o = 128; o > 0; o >>= 1) {
        if (threadIdx.x < o) red[threadIdx.x] += red[threadIdx.x + o];
        __syncthreads();
    }
    if (threadIdx.x == 0) partials[blockIdx.x] += red[0];
}

__global__ void zero_buf(float* __restrict__ p, int n) {
    int i = blockIdx.x * 256 + threadIdx.x;
    if (i < n) p[i] = 0.f;
}

// ---------------------------------------------------------------------------
extern "C" void kernel_launch(void* const* d_in, const int* in_sizes, int n_in,
                              void* d_out, int out_size, void* d_ws, size_t ws_size,
                              hipStream_t stream) {
    const float* I = (const float*)d_in[0];
    const float* T = (const float*)d_in[1];
    float* out = (float*)d_out;
    float* ws  = (float*)d_ws;

    const size_t szB1 = 11059200;    // scale0 x-sums (padded 60)
    const size_t szB2 = 3283200;
    const size_t szB3 = 974700;
    const size_t need = (szB1 + szB2 + szB3 + 1024) * sizeof(float);  // ~61.3 MB

    if (ws_size >= need) {
        float* B1 = ws;
        float* B2 = B1 + szB1;
        float* B3 = B2 + szB2;
        float* partials = B3 + szB3;
        pass1_s0<<<4608, 256, 0, stream>>>(I, T, B1);
        passY_s0<<<3207, 256, 0, stream>>>(B1, (float4*)B2);
        passZ_s0<<<952, 256, 0, stream>>>(B2, (float4*)B3);
        reduce_all<<<256, 256, 0, stream>>>(B3, partials);
        finalize_n<<<1, 256, 0, stream>>>(partials, 256, out);
    } else {
        // minimal-ws path: per scale, per channel pipelines (scalar, unpadded)
        const int   Ks[3] = {12, 24, 48};
        const int   Ss[3] = {3, 6, 12};
        const int   Os[3] = {57, 25, 9};
        const int   N1[3] = {2101248, 921600, 331776};
        const int   N2[3] = {623808, 120000, 15552};
        const int   N3[3] = {185193, 15625, 729};
        const float Wt[3] = {0.1f, 0.3f, 0.6f};

        float* B1 = ws;                 // n1_max = 2101248
        float* B2 = B1 + 2101248;       // n2_max = 623808
        float* B3 = B2 + 623808;        // 5 * n3_max = 925965
        float* partials = B3 + 925965;  // 256

        zero_buf<<<1, 256, 0, stream>>>(partials, 256);
        for (int sc = 0; sc < 3; ++sc) {
            int k = Ks[sc], s = Ss[sc], O = Os[sc];
            int n1 = N1[sc], n2 = N2[sc], n3 = N3[sc];
            for (int c = 0; c < 5; ++c) {
                pass1_one<<<(n1 + 255) / 256, 256, 0, stream>>>(I, T, B1, O, s, k, c);
                pass_y<<<(n2 + 255) / 256, 256, 0, stream>>>(B1, B2, O, s, k, n1, n2);
                pass_z<<<(n3 + 255) / 256, 256, 0, stream>>>(B2, B3 + (size_t)c * n3, O, s, k, n2, n3);
            }
            int nblk = (n3 + 255) / 256; if (nblk > 256) nblk = 256;
            reduce_one<<<nblk, 256, 0, stream>>>(B3, n3, 1.f / ((float)k * k * k),
                                                 Wt[sc] / (float)n3, partials);
        }
        finalize_n<<<1, 256, 0, stream>>>(partials, 256, out);
    }
}